// Round 20
// baseline (48.708 us; speedup 1.0000x reference)
//
#include <hip/hip_runtime.h>
#include <hip/hip_bf16.h>
#include <hip/hip_fp8.h>

// AlignConLoss: loss = sum_j [ log(sum_i exp(cn_i . an_j)) - cn_j . an_j ]
// B = 8192, D = 256, fp32 inputs, scalar fp32 out. sim in [-1,1] -> no max.
//
// R19 -> R20: MFMA shape 16x16x128 -> 32x32x64 (mfma_scale f8f6f4).
// Same geometry/barriers/vmcnt/swizzle as R19. Halves MFMA instruction
// count, af 64->32 VGPR, acc 16; wave = 32 i-rows (wr=w). Epilogue:
// C/D 32x32 layout (m74/m101): col=lane&31, row=(reg&3)+8*(reg>>2)+4*(lane>>5)
// -> 16 exp + one shfl_xor(32) + one atomic (lane<32). A/B fragments use the
// identical per-lane K-byte map (h*32+[0,32) per K=64 window) -> correctness
// by bijectivity regardless of internal K wiring.

#define BROWS 8192
#define DIM   256

typedef int   i32x4  __attribute__((ext_vector_type(4)));
typedef int   i32x8  __attribute__((ext_vector_type(8)));
typedef float f32x16 __attribute__((ext_vector_type(16)));

__device__ __forceinline__ void gload_lds16(const void* g, void* l) {
  __builtin_amdgcn_global_load_lds(
      (const __attribute__((address_space(1))) unsigned int*)g,
      (__attribute__((address_space(3))) unsigned int*)l, 16, 0, 0);
}

__device__ __forceinline__ unsigned char to_e4m3(float v) {
  __hip_fp8_e4m3 t(v);
  return *reinterpret_cast<unsigned char*>(&t);
}

// ---------------------------------------------------------------------------
// Kernel 1: per-row L2 norms -> fp8 e4m3 normalized An/Cn; exact fp32 diag.
// One wave per row. Blocks 0..31 also zero colsum[8192].
// ---------------------------------------------------------------------------
__global__ __launch_bounds__(256) void prep_kernel(
    const float* __restrict__ E1, const float* __restrict__ E2,
    unsigned char* __restrict__ An8, unsigned char* __restrict__ Cn8,
    float* __restrict__ diag, float* __restrict__ colsum) {
  if (blockIdx.x < 32) colsum[blockIdx.x * 256 + threadIdx.x] = 0.f;

  const int w    = threadIdx.x >> 6;
  const int lane = threadIdx.x & 63;
  const int row  = blockIdx.x * 4 + w;
  const size_t base = (size_t)row * DIM + lane * 4;

  const float4 a = *(const float4*)(E1 + base);
  const float4 c = *(const float4*)(E2 + base);

  float sa  = a.x*a.x + a.y*a.y + a.z*a.z + a.w*a.w;
  float sc  = c.x*c.x + c.y*c.y + c.z*c.z + c.w*c.w;
  float sac = a.x*c.x + a.y*c.y + a.z*c.z + a.w*c.w;
#pragma unroll
  for (int o = 32; o > 0; o >>= 1) {
    sa  += __shfl_down(sa,  o);
    sc  += __shfl_down(sc,  o);
    sac += __shfl_down(sac, o);
  }
  const float inva = 1.0f / fmaxf(sqrtf(__shfl(sa, 0)), 1e-8f);
  const float invc = 1.0f / fmaxf(sqrtf(__shfl(sc, 0)), 1e-8f);

  uchar4 pa, pc;
  pa.x = to_e4m3(a.x * inva); pa.y = to_e4m3(a.y * inva);
  pa.z = to_e4m3(a.z * inva); pa.w = to_e4m3(a.w * inva);
  pc.x = to_e4m3(c.x * invc); pc.y = to_e4m3(c.y * invc);
  pc.z = to_e4m3(c.z * invc); pc.w = to_e4m3(c.w * invc);
  *(uchar4*)(An8 + base) = pa;
  *(uchar4*)(Cn8 + base) = pc;
  if (lane == 0) diag[row] = sac * inva * invc;
}

// ---------------------------------------------------------------------------
// Kernel 2: block = 128 i x 256 j (8 jtiles of 32), MX-fp8 mfma_scale
// 32x32x64 (scale=1.0). Grid = 64 itiles x 32 jgroups = 2048. LDS 48 KB.
// 4 waves, wave w owns i-rows [w*32, w*32+32); per jtile computes one
// 32x32 tile x 4 K-windows (4 MFMA), all 32 j-cols.
// Fragment map (A and B identical): lane l, window W -> row (l&31) bytes
// [W*64 + (l>>5)*32, +32), via 2 x ds_read_b128 at swizzled slots
// s = (W*4 + (l>>5)*2 + {0,1}) ^ (row&7).
// vmcnt budget (2 loads/stage, 1 atomic/jtile): top 4; {2,3,4,4,4,4,4,2}.
// ---------------------------------------------------------------------------
__global__ __launch_bounds__(256, 2) void gemm_colsum_kernel(
    const unsigned char* __restrict__ Cn8,   // contrast rows -> sim rows i
    const unsigned char* __restrict__ An8,   // anchor rows   -> sim cols j
    float* __restrict__ colsum) {
  __shared__ __align__(16) unsigned char ldsC[32768];     // [128 rows][256 B]
  __shared__ __align__(16) unsigned char ldsA[2][8192];   // [buf][32 r][256 B]

  const int tid  = threadIdx.x;
  const int lane = tid & 63;
  const int w    = tid >> 6;      // 4 waves; wave w -> i-rows w*32..w*32+31

  const int jgroup = blockIdx.x & 31;
  const int itile  = blockIdx.x >> 5;
  const int i0 = itile * 128;
  const int j0 = jgroup * 256;

  // staging geometry (per 16-row round): row sr, phys slot tid&15 holds
  // logical slot pl = (tid&15) ^ (sr&7)  [involution phys = log ^ (row&7)]
  const int sr = tid >> 4;
  const int pl = (tid & 15) ^ (sr & 7);
  const unsigned char* gC = Cn8 + (size_t)(i0 + sr) * DIM + pl * 16;
  const unsigned char* gA = An8 + (size_t)(j0 + sr) * DIM + pl * 16;

  auto stageA = [&](int jj, int buf) {     // 8 KB: 2 rounds x 16 rows
#pragma unroll
    for (int r = 0; r < 2; ++r)
      gload_lds16(gA + (size_t)(jj * 32 + r * 16) * DIM,
                  &ldsA[buf][0] + r * 4096 + w * 1024);
  };

#pragma unroll
  for (int r = 0; r < 8; ++r)              // C-panel: 8 rounds x 16 rows
    gload_lds16(gC + (size_t)(r * 16) * DIM, &ldsC[0] + r * 4096 + w * 1024);
  stageA(0, 0);
  stageA(1, 1);

  asm volatile("s_waitcnt vmcnt(4)" ::: "memory");   // C landed; A0,A1 fly
  __builtin_amdgcn_sched_barrier(0);
  __builtin_amdgcn_s_barrier();

  const int h  = lane >> 5;                // K half-window selector
  const int rl = lane & 31;
  const int SC = 0x7F7F7F7F;               // e8m0 127 -> scale 1.0

  i32x8 af[4];                             // C fragments: 4 windows, 32 VGPR
  {
    const int r = w * 32 + rl;
#pragma unroll
    for (int W = 0; W < 4; ++W) {
      const int s0 = (W * 4 + h * 2)     ^ (r & 7);
      const int s1 = (W * 4 + h * 2 + 1) ^ (r & 7);
      union { i32x4 hh[2]; i32x8 v; } u;
      u.hh[0] = *(const i32x4*)(&ldsC[0] + r * 256 + s0 * 16);
      u.hh[1] = *(const i32x4*)(&ldsC[0] + r * 256 + s1 * 16);
      af[W] = u.v;
    }
  }
  asm volatile("s_waitcnt lgkmcnt(0)" ::: "memory");
  __builtin_amdgcn_sched_barrier(0);

#pragma unroll
  for (int jj = 0; jj < 8; ++jj) {
    const int b = jj & 1;
    // entry wait = stage(jj) landed; newer ops outstanding:
    // jj0: A1(2)=2.  jj1: stage2(2)+at0(1)=3.
    // jj2-6: at(jj-2)+stage(jj+1)x2+at(jj-1)=4.  jj7: at5+at6=2.
    if (jj == 0)      asm volatile("s_waitcnt vmcnt(2)" ::: "memory");
    else if (jj == 1) asm volatile("s_waitcnt vmcnt(3)" ::: "memory");
    else if (jj == 7) asm volatile("s_waitcnt vmcnt(2)" ::: "memory");
    else              asm volatile("s_waitcnt vmcnt(4)" ::: "memory");
    __builtin_amdgcn_sched_barrier(0);
    __builtin_amdgcn_s_barrier();          // A(jj) visible to all waves

    i32x8 bf[4];                           // B fragments: all 32 j-cols
    {
      const int r = rl;                    // A-tile row = j-col within tile
#pragma unroll
      for (int W = 0; W < 4; ++W) {
        const int s0 = (W * 4 + h * 2)     ^ (r & 7);
        const int s1 = (W * 4 + h * 2 + 1) ^ (r & 7);
        union { i32x4 hh[2]; i32x8 v; } u;
        u.hh[0] = *(const i32x4*)(&ldsA[b][0] + r * 256 + s0 * 16);
        u.hh[1] = *(const i32x4*)(&ldsA[b][0] + r * 256 + s1 * 16);
        bf[W] = u.v;
      }
    }
    asm volatile("s_waitcnt lgkmcnt(0)" ::: "memory");
    __builtin_amdgcn_sched_barrier(0);     // rule #18
    __builtin_amdgcn_s_barrier();          // buf b fully consumed
    __builtin_amdgcn_sched_barrier(0);

    if (jj < 6) stageA(jj + 2, b);         // prefetch 2 ahead into freed buf
    __builtin_amdgcn_sched_barrier(0);

    f32x16 acc = {};
    __builtin_amdgcn_s_setprio(1);
#pragma unroll
    for (int W = 0; W < 4; ++W)
      acc = __builtin_amdgcn_mfma_scale_f32_32x32x64_f8f6f4(
          af[W], bf[W], acc, 0, 0, 0, SC, 0, SC);
    __builtin_amdgcn_s_setprio(0);
    __builtin_amdgcn_sched_barrier(0);

    // Epilogue: col partials over this wave's 32 i-rows.
    // C/D 32x32 layout (m74/m101): col = lane&31,
    // row = (reg&3)+8*(reg>>2)+4*(lane>>5) — lane halves cover disjoint rows.
    float s = 0.f;
#pragma unroll
    for (int r = 0; r < 16; ++r) s += __expf(acc[r]);
    s += __shfl_xor(s, 32);                // combine the two row-halves
    if (lane < 32)
      atomicAdd(&colsum[j0 + jj * 32 + lane], s);
    __builtin_amdgcn_sched_barrier(0);
  }
}

// ---------------------------------------------------------------------------
// Kernel 3: loss = sum_j log(colsum[j]) - diag[j].  Single block.
// ---------------------------------------------------------------------------
__global__ __launch_bounds__(256) void finalize_kernel(
    const float* __restrict__ colsum, const float* __restrict__ diag,
    float* __restrict__ out) {
  const int t = threadIdx.x;
  float s = 0.f;
  for (int j = t; j < BROWS; j += 256) s += logf(colsum[j]) - diag[j];
#pragma unroll
  for (int o = 32; o > 0; o >>= 1) s += __shfl_down(s, o);
  __shared__ float red[4];
  if ((t & 63) == 0) red[t >> 6] = s;
  __syncthreads();
  if (t == 0) out[0] = red[0] + red[1] + red[2] + red[3];
}

// ---------------------------------------------------------------------------
// ws layout (~4.07 MB):
//   [0, 2MiB)            Cn8 fp8 [8192*256]
//   [2MiB, 4MiB)         An8 fp8 [8192*256]
//   [4MiB, +32KiB)       colsum f32 [8192]
//   [4MiB+32K, +32KiB)   diag   f32 [8192]
// ---------------------------------------------------------------------------
extern "C" void kernel_launch(void* const* d_in, const int* in_sizes, int n_in,
                              void* d_out, int out_size, void* d_ws, size_t ws_size,
                              hipStream_t stream) {
  const float* E1 = (const float*)d_in[0];   // encoder_embedding1 -> anchors
  const float* E2 = (const float*)d_in[1];   // encoder_embedding2 -> contrast
  char* ws = (char*)d_ws;
  unsigned char* Cn8 = (unsigned char*)(ws);
  unsigned char* An8 = (unsigned char*)(ws + (size_t)2 * 1024 * 1024);
  float* colsum = (float*)(ws + (size_t)4 * 1024 * 1024);
  float* diag   = (float*)(ws + (size_t)4 * 1024 * 1024 + 32 * 1024);
  float* out = (float*)d_out;

  prep_kernel<<<BROWS / 4, 256, 0, stream>>>(E1, E2, An8, Cn8, diag, colsum);
  gemm_colsum_kernel<<<64 * 32, 256, 0, stream>>>(Cn8, An8, colsum);
  finalize_kernel<<<1, 256, 0, stream>>>(colsum, diag, out);
}

// Round 21
// 47.059 us; speedup vs baseline: 1.0350x; 1.0350x over previous
//
#include <hip/hip_runtime.h>
#include <hip/hip_bf16.h>
#include <hip/hip_fp8.h>

// AlignConLoss: loss = sum_j [ log(sum_i exp(cn_i . an_j)) - cn_j . an_j ]
// B = 8192, D = 256, fp32 inputs, scalar fp32 out. sim in [-1,1] -> no max.
//
// R20 -> R21: software-pipelined bf (T3 mechanism, minimal form): iteration
// jj issues the ds_reads for jtile jj+1 right after A(jj+1)'s visibility
// barrier, then runs MFMA(jj)+epilogue(jj) on registers read last iteration.
// LDS-read latency and the exp epilogue now hide under MFMA instead of
// serializing. Same barriers/jtile (2), same staging/swizzle/shape as R20
// (32x32x64 MX-fp8, scale=1.0). bf reg-dbuf: +32 VGPR (~137, no cap).
// vmcnt (issue order, atomics counted): prologue 4 then 2;
// loop {jj0:2, jj1-5:3, jj6:1}.

#define BROWS 8192
#define DIM   256

typedef int   i32x4  __attribute__((ext_vector_type(4)));
typedef int   i32x8  __attribute__((ext_vector_type(8)));
typedef float f32x16 __attribute__((ext_vector_type(16)));

__device__ __forceinline__ void gload_lds16(const void* g, void* l) {
  __builtin_amdgcn_global_load_lds(
      (const __attribute__((address_space(1))) unsigned int*)g,
      (__attribute__((address_space(3))) unsigned int*)l, 16, 0, 0);
}

__device__ __forceinline__ unsigned char to_e4m3(float v) {
  __hip_fp8_e4m3 t(v);
  return *reinterpret_cast<unsigned char*>(&t);
}

// ---------------------------------------------------------------------------
// Kernel 1: per-row L2 norms -> fp8 e4m3 normalized An/Cn; exact fp32 diag.
// One wave per row. Blocks 0..31 also zero colsum[8192].
// ---------------------------------------------------------------------------
__global__ __launch_bounds__(256) void prep_kernel(
    const float* __restrict__ E1, const float* __restrict__ E2,
    unsigned char* __restrict__ An8, unsigned char* __restrict__ Cn8,
    float* __restrict__ diag, float* __restrict__ colsum) {
  if (blockIdx.x < 32) colsum[blockIdx.x * 256 + threadIdx.x] = 0.f;

  const int w    = threadIdx.x >> 6;
  const int lane = threadIdx.x & 63;
  const int row  = blockIdx.x * 4 + w;
  const size_t base = (size_t)row * DIM + lane * 4;

  const float4 a = *(const float4*)(E1 + base);
  const float4 c = *(const float4*)(E2 + base);

  float sa  = a.x*a.x + a.y*a.y + a.z*a.z + a.w*a.w;
  float sc  = c.x*c.x + c.y*c.y + c.z*c.z + c.w*c.w;
  float sac = a.x*c.x + a.y*c.y + a.z*c.z + a.w*c.w;
#pragma unroll
  for (int o = 32; o > 0; o >>= 1) {
    sa  += __shfl_down(sa,  o);
    sc  += __shfl_down(sc,  o);
    sac += __shfl_down(sac, o);
  }
  const float inva = 1.0f / fmaxf(sqrtf(__shfl(sa, 0)), 1e-8f);
  const float invc = 1.0f / fmaxf(sqrtf(__shfl(sc, 0)), 1e-8f);

  uchar4 pa, pc;
  pa.x = to_e4m3(a.x * inva); pa.y = to_e4m3(a.y * inva);
  pa.z = to_e4m3(a.z * inva); pa.w = to_e4m3(a.w * inva);
  pc.x = to_e4m3(c.x * invc); pc.y = to_e4m3(c.y * invc);
  pc.z = to_e4m3(c.z * invc); pc.w = to_e4m3(c.w * invc);
  *(uchar4*)(An8 + base) = pa;
  *(uchar4*)(Cn8 + base) = pc;
  if (lane == 0) diag[row] = sac * inva * invc;
}

// ---------------------------------------------------------------------------
// Kernel 2: block = 128 i x 256 j (8 jtiles of 32), MX-fp8 mfma_scale
// 32x32x64 (scale=1.0). Grid = 64 itiles x 32 jgroups = 2048. LDS 48 KB.
// Wave w owns i-rows [w*32, +32). Per jtile: 4 MFMA, 16 exp, 1 atomic.
// PIPELINE: bf(jj+1) ds_reads issued before MFMA(jj); lgkmcnt(0) for them
// only at the top of iteration jj+1. Barriers: consumed(buf b) + visible
// (A(jj+1)) per jtile, as before.
// ---------------------------------------------------------------------------
__global__ __launch_bounds__(256, 2) void gemm_colsum_kernel(
    const unsigned char* __restrict__ Cn8,   // contrast rows -> sim rows i
    const unsigned char* __restrict__ An8,   // anchor rows   -> sim cols j
    float* __restrict__ colsum) {
  __shared__ __align__(16) unsigned char ldsC[32768];     // [128 rows][256 B]
  __shared__ __align__(16) unsigned char ldsA[2][8192];   // [buf][32 r][256 B]

  const int tid  = threadIdx.x;
  const int lane = tid & 63;
  const int w    = tid >> 6;      // 4 waves; wave w -> i-rows w*32..w*32+31

  const int jgroup = blockIdx.x & 31;
  const int itile  = blockIdx.x >> 5;
  const int i0 = itile * 128;
  const int j0 = jgroup * 256;

  // staging geometry (16-row rounds): row sr, phys slot tid&15 holds
  // logical slot pl = (tid&15) ^ (sr&7)  [involution phys = log ^ (row&7)]
  const int sr = tid >> 4;
  const int pl = (tid & 15) ^ (sr & 7);
  const unsigned char* gC = Cn8 + (size_t)(i0 + sr) * DIM + pl * 16;
  const unsigned char* gA = An8 + (size_t)(j0 + sr) * DIM + pl * 16;

  auto stageA = [&](int jj, int buf) {     // 8 KB: 2 rounds x 16 rows
#pragma unroll
    for (int r = 0; r < 2; ++r)
      gload_lds16(gA + (size_t)(jj * 32 + r * 16) * DIM,
                  &ldsA[buf][0] + r * 4096 + w * 1024);
  };

#pragma unroll
  for (int r = 0; r < 8; ++r)              // C-panel: 8 rounds x 16 rows
    gload_lds16(gC + (size_t)(r * 16) * DIM, &ldsC[0] + r * 4096 + w * 1024);
  stageA(0, 0);
  stageA(1, 1);

  asm volatile("s_waitcnt vmcnt(4)" ::: "memory");   // C landed; A0,A1 fly
  __builtin_amdgcn_sched_barrier(0);
  __builtin_amdgcn_s_barrier();

  const int h  = lane >> 5;                // K half-window selector
  const int rl = lane & 31;
  const int SC = 0x7F7F7F7F;               // e8m0 127 -> scale 1.0

  i32x8 af[4];                             // C fragments: 4 windows, 32 VGPR
  {
    const int r = w * 32 + rl;
#pragma unroll
    for (int W = 0; W < 4; ++W) {
      const int s0 = (W * 4 + h * 2)     ^ (r & 7);
      const int s1 = (W * 4 + h * 2 + 1) ^ (r & 7);
      union { i32x4 hh[2]; i32x8 v; } u;
      u.hh[0] = *(const i32x4*)(&ldsC[0] + r * 256 + s0 * 16);
      u.hh[1] = *(const i32x4*)(&ldsC[0] + r * 256 + s1 * 16);
      af[W] = u.v;
    }
  }
  // (ldsC is never rewritten -> no consumed-barrier needed for it)

  i32x8 bf[2][4];                          // reg double-set for pipelining
  auto readB = [&](int set, int buf) {     // 8 ds_read_b128, swizzled
    const int r = rl;                      // A-tile row = j-col within tile
#pragma unroll
    for (int W = 0; W < 4; ++W) {
      const int s0 = (W * 4 + h * 2)     ^ (r & 7);
      const int s1 = (W * 4 + h * 2 + 1) ^ (r & 7);
      union { i32x4 hh[2]; i32x8 v; } u;
      u.hh[0] = *(const i32x4*)(&ldsA[buf][0] + r * 256 + s0 * 16);
      u.hh[1] = *(const i32x4*)(&ldsA[buf][0] + r * 256 + s1 * 16);
      bf[set][W] = u.v;
    }
  };

  asm volatile("s_waitcnt vmcnt(2)" ::: "memory");   // A0 landed (A1 flies)
  __builtin_amdgcn_sched_barrier(0);
  __builtin_amdgcn_s_barrier();            // A0 visible to all waves
  readB(0, 0);                             // issue bf(0) reads (no wait yet)

#pragma unroll
  for (int jj = 0; jj < 8; ++jj) {
    const int b = jj & 1;                  // loop unrolled -> b is constant
    asm volatile("s_waitcnt lgkmcnt(0)" ::: "memory"); // bf(jj) regs ready
    __builtin_amdgcn_sched_barrier(0);     // rule #18
    __builtin_amdgcn_s_barrier();          // all waves consumed buf b
    __builtin_amdgcn_sched_barrier(0);

    if (jj < 6) stageA(jj + 2, b);         // overwrite freed buf
    __builtin_amdgcn_sched_barrier(0);

    if (jj < 7) {
      // wait A(jj+1) landed; newer outstanding (issue order):
      // jj0: stage2(2)=2.  jj1-5: at(jj-1)+stage(jj+2)(2)=3.  jj6: at5=1.
      if (jj == 0)      asm volatile("s_waitcnt vmcnt(2)" ::: "memory");
      else if (jj == 6) asm volatile("s_waitcnt vmcnt(1)" ::: "memory");
      else              asm volatile("s_waitcnt vmcnt(3)" ::: "memory");
      __builtin_amdgcn_sched_barrier(0);
      __builtin_amdgcn_s_barrier();        // A(jj+1) visible to all waves
      readB(b ^ 1, b ^ 1);                 // issue bf(jj+1) reads — NO wait;
      __builtin_amdgcn_sched_barrier(0);   // they overlap MFMA+epi below
    }

    f32x16 acc = {};
    __builtin_amdgcn_s_setprio(1);
#pragma unroll
    for (int W = 0; W < 4; ++W)
      acc = __builtin_amdgcn_mfma_scale_f32_32x32x64_f8f6f4(
          af[W], bf[b][W], acc, 0, 0, 0, SC, 0, SC);
    __builtin_amdgcn_s_setprio(0);

    // Epilogue: col partials over this wave's 32 i-rows.
    // C/D 32x32 layout (m74/m101): col = lane&31,
    // row = (reg&3)+8*(reg>>2)+4*(lane>>5) — lane halves cover disjoint rows.
    float s = 0.f;
#pragma unroll
    for (int r = 0; r < 16; ++r) s += __expf(acc[r]);
    s += __shfl_xor(s, 32);                // combine the two row-halves
    if (lane < 32)
      atomicAdd(&colsum[j0 + jj * 32 + lane], s);
    __builtin_amdgcn_sched_barrier(0);
  }
}

// ---------------------------------------------------------------------------
// Kernel 3: loss = sum_j log(colsum[j]) - diag[j].  Single block.
// ---------------------------------------------------------------------------
__global__ __launch_bounds__(256) void finalize_kernel(
    const float* __restrict__ colsum, const float* __restrict__ diag,
    float* __restrict__ out) {
  const int t = threadIdx.x;
  float s = 0.f;
  for (int j = t; j < BROWS; j += 256) s += logf(colsum[j]) - diag[j];
#pragma unroll
  for (int o = 32; o > 0; o >>= 1) s += __shfl_down(s, o);
  __shared__ float red[4];
  if ((t & 63) == 0) red[t >> 6] = s;
  __syncthreads();
  if (t == 0) out[0] = red[0] + red[1] + red[2] + red[3];
}

// ---------------------------------------------------------------------------
// ws layout (~4.07 MB):
//   [0, 2MiB)            Cn8 fp8 [8192*256]
//   [2MiB, 4MiB)         An8 fp8 [8192*256]
//   [4MiB, +32KiB)       colsum f32 [8192]
//   [4MiB+32K, +32KiB)   diag   f32 [8192]
// ---------------------------------------------------------------------------
extern "C" void kernel_launch(void* const* d_in, const int* in_sizes, int n_in,
                              void* d_out, int out_size, void* d_ws, size_t ws_size,
                              hipStream_t stream) {
  const float* E1 = (const float*)d_in[0];   // encoder_embedding1 -> anchors
  const float* E2 = (const float*)d_in[1];   // encoder_embedding2 -> contrast
  char* ws = (char*)d_ws;
  unsigned char* Cn8 = (unsigned char*)(ws);
  unsigned char* An8 = (unsigned char*)(ws + (size_t)2 * 1024 * 1024);
  float* colsum = (float*)(ws + (size_t)4 * 1024 * 1024);
  float* diag   = (float*)(ws + (size_t)4 * 1024 * 1024 + 32 * 1024);
  float* out = (float*)d_out;

  prep_kernel<<<BROWS / 4, 256, 0, stream>>>(E1, E2, An8, Cn8, diag, colsum);
  gemm_colsum_kernel<<<64 * 32, 256, 0, stream>>>(Cn8, An8, colsum);
  finalize_kernel<<<1, 256, 0, stream>>>(colsum, diag, out);
}